// Round 5
// baseline (354.260 us; speedup 1.0000x reference)
//
#include <hip/hip_runtime.h>
#include <hip/hip_bf16.h>
#include <math.h>

#define BNEPS 1e-5f
#define BDIM_B 128
#define CDIM 512
#define SS 121
#define KK 9
#define MROWS (BDIM_B * SS)   // 15488

typedef unsigned short u16;
typedef __bf16 bf16x8 __attribute__((ext_vector_type(8)));
typedef float f32x4 __attribute__((ext_vector_type(4)));

__device__ __forceinline__ u16 f2bf(float f) {
    union { float f; unsigned int u; } v; v.f = f;
    unsigned int r = v.u + 0x7FFF + ((v.u >> 16) & 1);   // RNE
    return (u16)(r >> 16);
}
__device__ __forceinline__ float bf2f(u16 v) {
    union { unsigned int u; float f; } x; x.u = ((unsigned int)v) << 16; return x.f;
}

__device__ __forceinline__ void gld16(const u16* g, u16* l) {
    __builtin_amdgcn_global_load_lds(
        (const __attribute__((address_space(1))) void*)g,
        (__attribute__((address_space(3))) void*)l, 16, 0, 0);
}

// ---------------------------------------------------------------------------
// bf16 MFMA GEMM, 128x128 tile, BK=32, 256 threads (4 waves, 2x2 wave grid).
// Linear grid of (M/128)*(NT) blocks; bx=lb/NT (M-tile), by=lb%NT (N-tile).
// With round-robin block->XCD dispatch and NT==8, XCD x owns N-panel x for
// all M-panels: B stays L2-resident, A-panels stream in lockstep (L3 bcast).
// LDS XOR-swizzle: store chunk kq^((row>>1)&3); read chunk (lane>>4)^(((lane&15)>>1)&3).
// A: (M,Kd) bf16 row-major.  Bw: (N,Kd) bf16 row-major (B^T form).
// epilogue: v = (acc + bias[n]) * g[n]/sqrt(1+eps) + bb[n]
// MODE 1: relu -> bf16 store to Yout[(m%121)*128 + m/121][n]  (p-major remap)
// MODE 2: block rows all one p (= bx); relu, reduce over 128 rows ->
//         fp32 asum[p*N + n]  (fused relu->batch-sum)
// MODE 3: relu -> bf16 store Yout[m*N+n]
// MODE 4: sigmoid -> bf16 store Yout[m*N+n]
// ---------------------------------------------------------------------------
template<int MODE>
__global__ __launch_bounds__(256)
void gemm_mfma(const u16* __restrict__ A, const u16* __restrict__ Bw,
               const float* __restrict__ bias, const float* __restrict__ g,
               const float* __restrict__ bb, void* __restrict__ out,
               int Kd, int N, int NT)
{
    __shared__ __align__(16) u16 Als[128 * 32];
    __shared__ __align__(16) u16 Bls[128 * 32];

    const int tid  = threadIdx.x;
    const int lane = tid & 63;
    const int w    = tid >> 6;
    const int wm   = w >> 1, wn = w & 1;
    const int lb   = blockIdx.x;
    const int bx   = lb / NT;
    const int by   = lb - bx * NT;
    const int bm   = bx * 128;
    const int bn   = by * 128;

    f32x4 acc[4][4] = {};

    const int subrow = tid >> 2;         // 0..63
    const int kq     = tid & 3;          // 16B chunk within 32-elem k-row
    const int gchunk = kq ^ ((subrow >> 1) & 3);   // XOR-swizzled source chunk
    const u16* Ab = A  + (size_t)(bm + subrow) * Kd + gchunk * 8;
    const u16* Bb = Bw + (size_t)(bn + subrow) * Kd + gchunk * 8;
    u16* Al0 = &Als[(w * 16) * 32];
    u16* Al1 = &Als[(w * 16 + 64) * 32];
    u16* Bl0 = &Bls[(w * 16) * 32];
    u16* Bl1 = &Bls[(w * 16 + 64) * 32];

    const int fa_row = wm * 64 + (lane & 15);
    const int fb_row = wn * 64 + (lane & 15);
    const int kofs   = (((lane >> 4) ^ (((lane & 15) >> 1) & 3))) * 8;  // swizzled read chunk

    for (int k0 = 0; k0 < Kd; k0 += 32) {
        __syncthreads();
        gld16(Ab + k0, Al0);
        gld16(Ab + (size_t)64 * Kd + k0, Al1);
        gld16(Bb + k0, Bl0);
        gld16(Bb + (size_t)64 * Kd + k0, Bl1);
        __syncthreads();

        bf16x8 af[4], bfv[4];
        #pragma unroll
        for (int i = 0; i < 4; ++i)
            af[i] = *(bf16x8*)&Als[(fa_row + i * 16) * 32 + kofs];
        #pragma unroll
        for (int j = 0; j < 4; ++j)
            bfv[j] = *(bf16x8*)&Bls[(fb_row + j * 16) * 32 + kofs];
        #pragma unroll
        for (int i = 0; i < 4; ++i)
            #pragma unroll
            for (int j = 0; j < 4; ++j)
                acc[i][j] = __builtin_amdgcn_mfma_f32_16x16x32_bf16(af[i], bfv[j], acc[i][j], 0, 0, 0);
    }

    const float inv = 1.0f / sqrtf(1.0f + BNEPS);

    if (MODE == 1) {
        u16* Y = (u16*)out;
        int dstrow[4][4];
        #pragma unroll
        for (int i = 0; i < 4; ++i) {
            int mb = bm + wm * 64 + i * 16 + (lane >> 4) * 4;
            #pragma unroll
            for (int r = 0; r < 4; ++r) {
                int m = mb + r;
                int b = m / 121, p = m - b * 121;
                dstrow[i][r] = p * 128 + b;
            }
        }
        #pragma unroll
        for (int j = 0; j < 4; ++j) {
            int n = bn + wn * 64 + j * 16 + (lane & 15);
            float sc = g[n] * inv, bo = bias[n], bv = bb[n];
            #pragma unroll
            for (int i = 0; i < 4; ++i)
                #pragma unroll
                for (int r = 0; r < 4; ++r) {
                    float v = (acc[i][j][r] + bo) * sc + bv;
                    v = fmaxf(v, 0.0f);
                    Y[(size_t)dstrow[i][r] * N + n] = f2bf(v);
                }
        }
    } else if (MODE == 2) {
        float ps[4];
        #pragma unroll
        for (int j = 0; j < 4; ++j) {
            int n = bn + wn * 64 + j * 16 + (lane & 15);
            float sc = g[n] * inv, bo = bias[n], bv = bb[n];
            float s = 0.f;
            #pragma unroll
            for (int i = 0; i < 4; ++i)
                #pragma unroll
                for (int r = 0; r < 4; ++r) {
                    float v = (acc[i][j][r] + bo) * sc + bv;
                    s += fmaxf(v, 0.0f);
                }
            ps[j] = s;
        }
        __syncthreads();
        float* red = (float*)Als;
        #pragma unroll
        for (int j = 0; j < 4; ++j)
            red[(wm * 4 + (lane >> 4)) * 128 + wn * 64 + j * 16 + (lane & 15)] = ps[j];
        __syncthreads();
        if (tid < 128) {
            float s = 0.f;
            #pragma unroll
            for (int r = 0; r < 8; ++r) s += red[r * 128 + tid];
            ((float*)out)[(size_t)bx * N + bn + tid] = s;
        }
    } else {
        u16* Y = (u16*)out;
        #pragma unroll
        for (int j = 0; j < 4; ++j) {
            int n = bn + wn * 64 + j * 16 + (lane & 15);
            float sc = g[n] * inv, bo = bias[n], bv = bb[n];
            #pragma unroll
            for (int i = 0; i < 4; ++i) {
                int mb = bm + wm * 64 + i * 16 + (lane >> 4) * 4;
                #pragma unroll
                for (int r = 0; r < 4; ++r) {
                    float v = (acc[i][j][r] + bo) * sc + bv;
                    if (MODE == 3) v = fmaxf(v, 0.0f);
                    else           v = 1.f / (1.f + expf(-v));
                    Y[(size_t)(mb + r) * N + n] = f2bf(v);
                }
            }
        }
    }
}

// x (B,C,11,11) fp32 -> Xb[(b*121+p)*512 + c] bf16  (LDS tile transpose)
__global__ void transpose_x(const float* __restrict__ x, u16* __restrict__ Xb)
{
    __shared__ float t[64 * 121];
    int b = blockIdx.x, c0 = blockIdx.y * 64;
    for (int idx = threadIdx.x; idx < 64 * 121; idx += 256) {
        int c = idx / 121, p = idx - c * 121;
        t[idx] = x[((size_t)b * 512 + c0 + c) * 121 + p];
    }
    __syncthreads();
    for (int idx = threadIdx.x; idx < 121 * 64; idx += 256) {
        int p = idx >> 6, c = idx & 63;
        Xb[((size_t)(b * 121 + p)) * 512 + c0 + c] = f2bf(t[c * 121 + p]);
    }
}

// all four big weight matrices -> bf16, one launch
#define W1N (1024 * 512)
#define W2N (1024 * 1024)
#define L1N (1024 * 1024)
#define L2N (512 * 1024)
__global__ void conv_weights(const float* __restrict__ w1, const float* __restrict__ w2,
                             const float* __restrict__ l1, const float* __restrict__ l2,
                             u16* __restrict__ o1, u16* __restrict__ o2,
                             u16* __restrict__ o3, u16* __restrict__ o4)
{
    int i = blockIdx.x * 256 + threadIdx.x;
    if (i < W1N) { o1[i] = f2bf(w1[i]); return; }
    i -= W1N;
    if (i < W2N) { o2[i] = f2bf(w2[i]); return; }
    i -= W2N;
    if (i < L1N) { o3[i] = f2bf(l1[i]); return; }
    i -= L1N;
    if (i < L2N) { o4[i] = f2bf(l2[i]); }
}

__global__ void f32_to_bf16(const float* __restrict__ in, u16* __restrict__ out, int n)
{
    int i = blockIdx.x * 256 + threadIdx.x;
    if (i < n) out[i] = f2bf(in[i]);
}

// dctT[p*512+c] = dct[c*121+p]
__global__ void transpose_dct(const float* __restrict__ dct, float* __restrict__ dctT)
{
    int idx = blockIdx.x * 256 + threadIdx.x;
    if (idx >= 512 * 121) return;
    int p = idx >> 9, c = idx & 511;
    dctT[idx] = dct[(size_t)c * 121 + p];
}

// ---------------------------------------------------------------------------
// spatial kernel: one wave per row of (rows,512) bf16 input.
// ---------------------------------------------------------------------------
__global__ __launch_bounds__(256)
void rowdot9(const u16* __restrict__ Xb, const u16* __restrict__ Xt,
             const float* __restrict__ w_conv, const float* __restrict__ b_conv,
             const float* __restrict__ g_sp, const float* __restrict__ b_sp,
             float* __restrict__ skb, float* __restrict__ skt)
{
    int wid = (blockIdx.x * 256 + threadIdx.x) >> 6;   // global wave id = row
    int lane = threadIdx.x & 63;
    if (wid >= MROWS + SS) return;                      // wave-uniform
    const u16* src = (wid < MROWS) ? Xb + (size_t)wid * 512
                                   : Xt + (size_t)(wid - MROWS) * 512;
    bf16x8 xv = *(const bf16x8*)(src + lane * 8);
    float xf[8];
    #pragma unroll
    for (int j = 0; j < 8; ++j) xf[j] = (float)xv[j];

    float s[9];
    #pragma unroll
    for (int k9 = 0; k9 < 9; ++k9) {
        const float* wr = w_conv + k9 * 512 + lane * 8;
        float4 w0 = *(const float4*)wr;
        float4 w1 = *(const float4*)(wr + 4);
        s[k9] = xf[0] * w0.x + xf[1] * w0.y + xf[2] * w0.z + xf[3] * w0.w
              + xf[4] * w1.x + xf[5] * w1.y + xf[6] * w1.z + xf[7] * w1.w;
    }
    #pragma unroll
    for (int off = 1; off < 64; off <<= 1)
        #pragma unroll
        for (int k9 = 0; k9 < 9; ++k9)
            s[k9] += __shfl_xor(s[k9], off);

    if (lane < 9) {
        int p = wid % 121;
        float v = (s[lane] + b_conv[lane]) * (g_sp[p] * (1.0f / sqrtf(1.0f + BNEPS))) + b_sp[p];
        float* dst = (wid < MROWS) ? skb + (size_t)wid * 9 : skt + (size_t)(wid - MROWS) * 9;
        dst[lane] = v;
    }
}

// ---------------------------------------------------------------------------
// DCT pooling over (rows,512) bf16 input; thread = g*512+c, g==128 -> task.
// ---------------------------------------------------------------------------
__global__ void dct_pool_xb(const u16* __restrict__ Xb, const u16* __restrict__ Xt,
                            const float* __restrict__ dctT,
                            float* __restrict__ ybuf, float* __restrict__ y_t)
{
    int idx = blockIdx.x * 256 + threadIdx.x;
    if (idx >= 129 * 512) return;
    int g = idx >> 9, c = idx & 511;
    const u16* src = (g < 128) ? Xb + (size_t)g * 121 * 512 + c : Xt + c;
    float s = 0.f;
    for (int p = 0; p < SS; ++p)
        s += bf2f(src[(size_t)p * 512]) * dctT[p * 512 + c];
    if (g < 128) ybuf[idx] = s; else y_t[c] = s;
}

// fc1 (512->32, relu), 8-way k-split; block per g (g==128 -> task)
__global__ __launch_bounds__(256)
void fc1_fused(const float* __restrict__ ybuf, const float* __restrict__ y_t,
               const float* __restrict__ fc1, float* __restrict__ y2buf,
               float* __restrict__ y2_t)
{
    __shared__ float Als[512];
    int g = blockIdx.x;
    const float* a = (g < 128) ? ybuf + (size_t)g * 512 : y_t;
    for (int i = threadIdx.x; i < 128; i += 256)
        ((float4*)Als)[i] = ((const float4*)a)[i];
    __syncthreads();
    int o = threadIdx.x >> 3, kp = threadIdx.x & 7;
    const float* w = fc1 + (size_t)o * 512;
    float s = 0.f;
    for (int k = kp * 4; k < 512; k += 32) {
        float4 wv = *(const float4*)(w + k);
        float4 av = *(const float4*)(Als + k);
        s += wv.x * av.x + wv.y * av.y + wv.z * av.z + wv.w * av.w;
    }
    s += __shfl_xor(s, 1);
    s += __shfl_xor(s, 2);
    s += __shfl_xor(s, 4);
    if (kp == 0) {
        float v = fmaxf(s, 0.f);
        if (g < 128) y2buf[(size_t)g * 32 + o] = v; else y2_t[o] = v;
    }
}

// fc2 + sigmoid + channel BN; thread per output; g==128 -> task
__global__ void fc2_ck_fused(const float* __restrict__ y2buf, const float* __restrict__ y2_t,
                             const float* __restrict__ fc2,
                             const float* __restrict__ g_ch, const float* __restrict__ b_ch,
                             float* __restrict__ ckbuf, float* __restrict__ ck_t)
{
    int idx = blockIdx.x * 256 + threadIdx.x;
    if (idx >= 129 * CDIM * KK) return;
    int g = idx / (CDIM * KK), o = idx % (CDIM * KK);
    int c = o / KK;
    const float* yb = (g < 128) ? y2buf + (size_t)g * 32 : y2_t;
    const float* w = fc2 + (size_t)o * 32;
    float s = 0.f;
    #pragma unroll
    for (int k = 0; k < 32; ++k) s += yb[k] * w[k];
    s = 1.f / (1.f + expf(-s));
    s = s * (g_ch[c] * (1.0f / sqrtf(1.0f + BNEPS))) + b_ch[c];
    if (g < 128) ckbuf[idx] = s; else ck_t[o] = s;
}

// tk[c*1089 + p*9 + k9] = sk_t[p*9+k9] * ck_t[c*9+k9]
__global__ void task_kernel_write(const float* __restrict__ sk_t, const float* __restrict__ ck_t,
                                  float* __restrict__ tk)
{
    int idx = blockIdx.x * blockDim.x + threadIdx.x;
    if (idx >= CDIM * SS * KK) return;
    int k9 = idx % KK;
    int pc = idx / KK;
    int p = pc % SS, c = pc / SS;
    tk[idx] = sk_t[p * KK + k9] * ck_t[c * KK + k9];
}

// ---------------------------------------------------------------------------
// final: out0[b,c,p] = (1/9) sum_k unfold(x)[k] * PS[p,k] * CS[c,k] + x[b,c,p]
// ---------------------------------------------------------------------------
__global__ __launch_bounds__(256)
void final_v2(const float* __restrict__ x, const float* __restrict__ skb,
              const float* __restrict__ sk_t, const float* __restrict__ ckbuf,
              const float* __restrict__ ck_t, float* __restrict__ out0)
{
    __shared__ float PS[SS * KK];       // 1089 fp32
    __shared__ float CS[64 * KK];       // 576 fp32
    __shared__ float XT[64 * SS];       // 7744 fp32 (64 x-planes)
    const int tid = threadIdx.x;
    const int b = blockIdx.x, c0 = blockIdx.y * 64;

    const float* sp = skb + (size_t)b * SS * KK;
    for (int i = tid; i < SS * KK; i += 256) PS[i] = sp[i] * sk_t[i];
    const float* cp = ckbuf + ((size_t)b * CDIM + c0) * KK;
    const float* tp = ck_t + (size_t)c0 * KK;
    for (int i = tid; i < 64 * KK; i += 256) CS[i] = cp[i] * tp[i];
    const float* xp = x + ((size_t)b * CDIM + c0) * SS;
    for (int i = tid; i < 64 * SS; i += 256) XT[i] = xp[i];
    __syncthreads();

    float* op = out0 + ((size_t)b * CDIM + c0) * SS;
    for (int i = tid; i < 64 * SS; i += 256) {
        int c = i / SS, p = i - c * SS;
        int h = p / 11, w = p - h * 11;
        const float* xc = XT + c * SS;
        const float* ps = PS + p * KK;
        const float* cs = CS + c * KK;
        float acc = 0.f;
        #pragma unroll
        for (int di = 0; di < 3; ++di) {
            int hh = h + di - 1;
            bool hv = (unsigned)hh < 11u;
            #pragma unroll
            for (int dj = 0; dj < 3; ++dj) {
                int ww = w + dj - 1;
                int k = di * 3 + dj;
                float xv = (hv && (unsigned)ww < 11u) ? xc[hh * 11 + ww] : 0.f;
                acc += xv * ps[k] * cs[k];
            }
        }
        op[i] = acc * (1.0f / 9.0f) + xc[p];
    }
}

extern "C" void kernel_launch(void* const* d_in, const int* in_sizes, int n_in,
                              void* d_out, int out_size, void* d_ws, size_t ws_size,
                              hipStream_t stream)
{
    const float* x      = (const float*)d_in[0];
    const float* dct_w  = (const float*)d_in[1];
    const float* w_conv = (const float*)d_in[2];
    const float* b_conv = (const float*)d_in[3];
    const float* g_sp   = (const float*)d_in[4];
    const float* b_sp   = (const float*)d_in[5];
    const float* g_ch   = (const float*)d_in[6];
    const float* b_ch   = (const float*)d_in[7];
    const float* fc1    = (const float*)d_in[8];
    const float* fc2    = (const float*)d_in[9];
    const float* up_w1  = (const float*)d_in[10];
    const float* up_b1  = (const float*)d_in[11];
    const float* up_g1  = (const float*)d_in[12];
    const float* up_bb1 = (const float*)d_in[13];
    const float* up_w2  = (const float*)d_in[14];
    const float* up_b2  = (const float*)d_in[15];
    const float* up_g2  = (const float*)d_in[16];
    const float* up_bb2 = (const float*)d_in[17];
    const float* lo_w1  = (const float*)d_in[18];
    const float* lo_b1  = (const float*)d_in[19];
    const float* lo_g1  = (const float*)d_in[20];
    const float* lo_bb1 = (const float*)d_in[21];
    const float* lo_w2  = (const float*)d_in[22];
    const float* lo_b2  = (const float*)d_in[23];
    const float* lo_g2  = (const float*)d_in[24];
    const float* lo_bb2 = (const float*)d_in[25];

    float* out0 = (float*)d_out;                       // (B,C,11,11)
    float* tk   = out0 + (size_t)BDIM_B * CDIM * SS;   // (1,C,11,11,3,3)

    // workspace layout (bytes, 64B-aligned chunks)
    char* ws = (char*)d_ws;
    size_t off = 0;
    auto alloc = [&](size_t bytes) { void* p = ws + off; off += (bytes + 63) & ~(size_t)63; return p; };
    u16*   Xb      = (u16*)alloc((size_t)MROWS * 512 * 2);
    u16*   Y1      = (u16*)alloc((size_t)MROWS * 1024 * 2);
    u16*   w1b     = (u16*)alloc((size_t)W1N * 2);
    u16*   w2b     = (u16*)alloc((size_t)W2N * 2);
    u16*   lw1b    = (u16*)alloc((size_t)L1N * 2);
    u16*   lw2b    = (u16*)alloc((size_t)L2N * 2);
    float* asum    = (float*)alloc((size_t)128 * 1024 * 4);   // 128 rows (121 valid)
    u16*   asum_b  = (u16*)alloc((size_t)128 * 1024 * 2);
    u16*   a3b     = (u16*)alloc((size_t)128 * 1024 * 2);
    u16*   ts_pc   = (u16*)alloc((size_t)128 * 512 * 2);      // task_s (p,c) bf16, 128 rows
    float* dctT    = (float*)alloc((size_t)SS * 512 * 4);
    float* ybuf    = (float*)alloc((size_t)BDIM_B * CDIM * 4);
    float* y2buf   = (float*)alloc((size_t)BDIM_B * 32 * 4);
    float* ckbuf   = (float*)alloc((size_t)BDIM_B * CDIM * KK * 4);
    float* skbuf   = (float*)alloc((size_t)BDIM_B * SS * KK * 4);
    float* y_t     = (float*)alloc((size_t)CDIM * 4);
    float* y2_t    = (float*)alloc((size_t)32 * 4);
    float* ck_t    = (float*)alloc((size_t)CDIM * KK * 4);
    float* sk_t    = (float*)alloc((size_t)SS * KK * 4);

    // --- prep: bf16 conversions + dct transpose ---
    hipLaunchKernelGGL(transpose_x, dim3(BDIM_B, 8), dim3(256), 0, stream, x, Xb);
    hipLaunchKernelGGL(conv_weights, dim3((W1N + W2N + L1N + L2N) / 256), dim3(256), 0, stream,
                       up_w1, up_w2, lo_w1, lo_w2, w1b, w2b, lw1b, lw2b);
    hipLaunchKernelGGL(transpose_dct, dim3((512 * 121 + 255) / 256), dim3(256), 0, stream,
                       dct_w, dctT);

    // --- up path: two MFMA GEMMs (linear grid, XCD-swizzled) ---
    hipLaunchKernelGGL((gemm_mfma<1>), dim3(121 * 8), dim3(256), 0, stream,
                       Xb, w1b, up_b1, up_g1, up_bb1, (void*)Y1, 512, 1024, 8);
    hipLaunchKernelGGL((gemm_mfma<2>), dim3(121 * 8), dim3(256), 0, stream,
                       Y1, w2b, up_b2, up_g2, up_bb2, (void*)asum, 1024, 1024, 8);

    // --- lo path: MFMA GEMMs on padded M=128 (rows 121..127 garbage, unread) ---
    hipLaunchKernelGGL(f32_to_bf16, dim3((128 * 1024) / 256), dim3(256), 0, stream,
                       asum, asum_b, 128 * 1024);
    hipLaunchKernelGGL((gemm_mfma<3>), dim3(8), dim3(256), 0, stream,
                       asum_b, lw1b, lo_b1, lo_g1, lo_bb1, (void*)a3b, 1024, 1024, 8);
    hipLaunchKernelGGL((gemm_mfma<4>), dim3(4), dim3(256), 0, stream,
                       a3b, lw2b, lo_b2, lo_g2, lo_bb2, (void*)ts_pc, 1024, 512, 4);

    // --- spatial kernels (instance + task fused): wave per row ---
    hipLaunchKernelGGL(rowdot9, dim3((MROWS + SS + 3) / 4), dim3(256), 0, stream,
                       Xb, ts_pc, w_conv, b_conv, g_sp, b_sp, skbuf, sk_t);

    // --- channel kernels (instance + task fused) ---
    hipLaunchKernelGGL(dct_pool_xb, dim3((129 * 512) / 256), dim3(256), 0, stream,
                       Xb, ts_pc, dctT, ybuf, y_t);
    hipLaunchKernelGGL(fc1_fused, dim3(129), dim3(256), 0, stream,
                       ybuf, y_t, fc1, y2buf, y2_t);
    hipLaunchKernelGGL(fc2_ck_fused, dim3((129 * CDIM * KK + 255) / 256), dim3(256), 0, stream,
                       y2buf, y2_t, fc2, g_ch, b_ch, ckbuf, ck_t);

    // --- task kernel output ---
    hipLaunchKernelGGL(task_kernel_write, dim3((CDIM * SS * KK + 255) / 256), dim3(256), 0, stream,
                       sk_t, ck_t, tk);

    // --- final fused: factorized kernel product, LDS-staged ---
    hipLaunchKernelGGL(final_v2, dim3(BDIM_B, 8), dim3(256), 0, stream,
                       x, skbuf, sk_t, ckbuf, ck_t, out0);
}

// Round 6
// 351.694 us; speedup vs baseline: 1.0073x; 1.0073x over previous
//
#include <hip/hip_runtime.h>
#include <hip/hip_bf16.h>
#include <math.h>

#define BNEPS 1e-5f
#define BDIM_B 128
#define CDIM 512
#define SS 121
#define KK 9
#define MROWS (BDIM_B * SS)   // 15488

typedef unsigned short u16;
typedef __bf16 bf16x8 __attribute__((ext_vector_type(8)));
typedef float f32x4 __attribute__((ext_vector_type(4)));

__device__ __forceinline__ u16 f2bf(float f) {
    union { float f; unsigned int u; } v; v.f = f;
    unsigned int r = v.u + 0x7FFF + ((v.u >> 16) & 1);   // RNE
    return (u16)(r >> 16);
}
__device__ __forceinline__ float bf2f(u16 v) {
    union { unsigned int u; float f; } x; x.u = ((unsigned int)v) << 16; return x.f;
}

__device__ __forceinline__ void gld16(const u16* g, u16* l) {
    __builtin_amdgcn_global_load_lds(
        (const __attribute__((address_space(1))) void*)g,
        (__attribute__((address_space(3))) void*)l, 16, 0, 0);
}

// ---------------------------------------------------------------------------
// bf16 MFMA GEMM, 128x128 tile, BK=32, 256 threads (4 waves, 2x2 wave grid).
// SWIZ=1 (grid 968, Mtiles=121, NT=8): XCD g (= blockIdx%8) owns M-chunk
//   bx in [g*15, g*15+15) and iterates all 8 N-tiles -> its 15 A-panels
//   (3.75 MB) + full B (2 MB) stay L2-resident; aggregate L2-fetch ~46 MB
//   instead of 8x full-A refetch. Tail blocks 960..967 cover bx=120.
// SWIZ=0: bx = i/NT, by = i%NT (lo-path small grids).
// LDS XOR-swizzle on staging/reads keeps bank conflicts ~0 (round-5 result).
// A: (M,Kd) bf16 row-major.  Bw: (N,Kd) bf16 row-major (B^T form).
// epilogue: v = (acc + bias[n]) * g[n]/sqrt(1+eps) + bb[n]
// MODE 1: relu -> bf16 store to Yout[(m%121)*128 + m/121][n]  (p-major remap)
// MODE 2: block rows all one p (= bx); relu, reduce over 128 rows ->
//         bf16 asum_b[p*N + n]  (fused relu->batch-sum->bf16)
// MODE 3: relu -> bf16 store Yout[m*N+n]
// MODE 4: sigmoid -> bf16 store Yout[m*N+n]
// ---------------------------------------------------------------------------
template<int MODE, int SWIZ>
__global__ __launch_bounds__(256)
void gemm_mfma(const u16* __restrict__ A, const u16* __restrict__ Bw,
               const float* __restrict__ bias, const float* __restrict__ g,
               const float* __restrict__ bb, void* __restrict__ out,
               int Kd, int N, int NT)
{
    __shared__ __align__(16) u16 Als[128 * 32];
    __shared__ __align__(16) u16 Bls[128 * 32];

    const int tid  = threadIdx.x;
    const int lane = tid & 63;
    const int w    = tid >> 6;
    const int wm   = w >> 1, wn = w & 1;

    int bx, by;
    if (SWIZ) {
        int i = blockIdx.x;
        if (i < 960) {
            int xg = i & 7;            // XCD (round-robin block dispatch)
            int j  = i >> 3;           // 0..119
            bx = xg * 15 + (j >> 3);   // M-chunk owned by this XCD
            by = j & 7;
        } else { bx = 120; by = i - 960; }
    } else {
        bx = blockIdx.x / NT; by = blockIdx.x - bx * NT;
    }
    const int bm = bx * 128;
    const int bn = by * 128;

    f32x4 acc[4][4] = {};

    const int subrow = tid >> 2;         // 0..63
    const int kq     = tid & 3;          // 16B chunk within 32-elem k-row
    const int gchunk = kq ^ ((subrow >> 1) & 3);   // XOR-swizzled source chunk
    const u16* Ab = A  + (size_t)(bm + subrow) * Kd + gchunk * 8;
    const u16* Bb = Bw + (size_t)(bn + subrow) * Kd + gchunk * 8;
    u16* Al0 = &Als[(w * 16) * 32];
    u16* Al1 = &Als[(w * 16 + 64) * 32];
    u16* Bl0 = &Bls[(w * 16) * 32];
    u16* Bl1 = &Bls[(w * 16 + 64) * 32];

    const int fa_row = wm * 64 + (lane & 15);
    const int fb_row = wn * 64 + (lane & 15);
    const int kofs   = (((lane >> 4) ^ (((lane & 15) >> 1) & 3))) * 8;  // swizzled read chunk

    for (int k0 = 0; k0 < Kd; k0 += 32) {
        __syncthreads();
        gld16(Ab + k0, Al0);
        gld16(Ab + (size_t)64 * Kd + k0, Al1);
        gld16(Bb + k0, Bl0);
        gld16(Bb + (size_t)64 * Kd + k0, Bl1);
        __syncthreads();

        bf16x8 af[4], bfv[4];
        #pragma unroll
        for (int i = 0; i < 4; ++i)
            af[i] = *(bf16x8*)&Als[(fa_row + i * 16) * 32 + kofs];
        #pragma unroll
        for (int j = 0; j < 4; ++j)
            bfv[j] = *(bf16x8*)&Bls[(fb_row + j * 16) * 32 + kofs];
        #pragma unroll
        for (int i = 0; i < 4; ++i)
            #pragma unroll
            for (int j = 0; j < 4; ++j)
                acc[i][j] = __builtin_amdgcn_mfma_f32_16x16x32_bf16(af[i], bfv[j], acc[i][j], 0, 0, 0);
    }

    const float inv = 1.0f / sqrtf(1.0f + BNEPS);

    if (MODE == 1) {
        u16* Y = (u16*)out;
        int dstrow[4][4];
        #pragma unroll
        for (int i = 0; i < 4; ++i) {
            int mb = bm + wm * 64 + i * 16 + (lane >> 4) * 4;
            #pragma unroll
            for (int r = 0; r < 4; ++r) {
                int m = mb + r;
                int b = m / 121, p = m - b * 121;
                dstrow[i][r] = p * 128 + b;
            }
        }
        #pragma unroll
        for (int j = 0; j < 4; ++j) {
            int n = bn + wn * 64 + j * 16 + (lane & 15);
            float sc = g[n] * inv, bo = bias[n], bv = bb[n];
            #pragma unroll
            for (int i = 0; i < 4; ++i)
                #pragma unroll
                for (int r = 0; r < 4; ++r) {
                    float v = (acc[i][j][r] + bo) * sc + bv;
                    v = fmaxf(v, 0.0f);
                    Y[(size_t)dstrow[i][r] * N + n] = f2bf(v);
                }
        }
    } else if (MODE == 2) {
        float ps[4];
        #pragma unroll
        for (int j = 0; j < 4; ++j) {
            int n = bn + wn * 64 + j * 16 + (lane & 15);
            float sc = g[n] * inv, bo = bias[n], bv = bb[n];
            float s = 0.f;
            #pragma unroll
            for (int i = 0; i < 4; ++i)
                #pragma unroll
                for (int r = 0; r < 4; ++r) {
                    float v = (acc[i][j][r] + bo) * sc + bv;
                    s += fmaxf(v, 0.0f);
                }
            ps[j] = s;
        }
        __syncthreads();
        float* red = (float*)Als;
        #pragma unroll
        for (int j = 0; j < 4; ++j)
            red[(wm * 4 + (lane >> 4)) * 128 + wn * 64 + j * 16 + (lane & 15)] = ps[j];
        __syncthreads();
        if (tid < 128) {
            float s = 0.f;
            #pragma unroll
            for (int r = 0; r < 8; ++r) s += red[r * 128 + tid];
            ((u16*)out)[(size_t)bx * N + bn + tid] = f2bf(s);
        }
    } else {
        u16* Y = (u16*)out;
        #pragma unroll
        for (int j = 0; j < 4; ++j) {
            int n = bn + wn * 64 + j * 16 + (lane & 15);
            float sc = g[n] * inv, bo = bias[n], bv = bb[n];
            #pragma unroll
            for (int i = 0; i < 4; ++i) {
                int mb = bm + wm * 64 + i * 16 + (lane >> 4) * 4;
                #pragma unroll
                for (int r = 0; r < 4; ++r) {
                    float v = (acc[i][j][r] + bo) * sc + bv;
                    if (MODE == 3) v = fmaxf(v, 0.0f);
                    else           v = 1.f / (1.f + expf(-v));
                    Y[(size_t)(mb + r) * N + n] = f2bf(v);
                }
            }
        }
    }
}

// x (B,C,11,11) fp32 -> Xb[(b*121+p)*512 + c] bf16  (LDS tile transpose)
__global__ void transpose_x(const float* __restrict__ x, u16* __restrict__ Xb)
{
    __shared__ float t[64 * 121];
    int b = blockIdx.x, c0 = blockIdx.y * 64;
    for (int idx = threadIdx.x; idx < 64 * 121; idx += 256) {
        int c = idx / 121, p = idx - c * 121;
        t[idx] = x[((size_t)b * 512 + c0 + c) * 121 + p];
    }
    __syncthreads();
    for (int idx = threadIdx.x; idx < 121 * 64; idx += 256) {
        int p = idx >> 6, c = idx & 63;
        Xb[((size_t)(b * 121 + p)) * 512 + c0 + c] = f2bf(t[c * 121 + p]);
    }
}

// all four big weight casts + dct transpose, one dispatch
#define W1N (1024 * 512)
#define W2N (1024 * 1024)
#define L1N (1024 * 1024)
#define L2N (512 * 1024)
#define DCTN (512 * 121)
__global__ void prep_all(const float* __restrict__ w1, const float* __restrict__ w2,
                         const float* __restrict__ l1, const float* __restrict__ l2,
                         const float* __restrict__ dct,
                         u16* __restrict__ o1, u16* __restrict__ o2,
                         u16* __restrict__ o3, u16* __restrict__ o4,
                         float* __restrict__ dctT)
{
    int i = blockIdx.x * 256 + threadIdx.x;
    if (i < W1N) { o1[i] = f2bf(w1[i]); return; }
    i -= W1N;
    if (i < W2N) { o2[i] = f2bf(w2[i]); return; }
    i -= W2N;
    if (i < L1N) { o3[i] = f2bf(l1[i]); return; }
    i -= L1N;
    if (i < L2N) { o4[i] = f2bf(l2[i]); return; }
    i -= L2N;
    if (i < DCTN) {
        int p = i >> 9, c = i & 511;
        dctT[i] = dct[(size_t)c * 121 + p];
    }
}

// ---------------------------------------------------------------------------
// spatial kernel: one wave per row of (rows,512) bf16 input.
// ---------------------------------------------------------------------------
__global__ __launch_bounds__(256)
void rowdot9(const u16* __restrict__ Xb, const u16* __restrict__ Xt,
             const float* __restrict__ w_conv, const float* __restrict__ b_conv,
             const float* __restrict__ g_sp, const float* __restrict__ b_sp,
             float* __restrict__ skb, float* __restrict__ skt)
{
    int wid = (blockIdx.x * 256 + threadIdx.x) >> 6;   // global wave id = row
    int lane = threadIdx.x & 63;
    if (wid >= MROWS + SS) return;                      // wave-uniform
    const u16* src = (wid < MROWS) ? Xb + (size_t)wid * 512
                                   : Xt + (size_t)(wid - MROWS) * 512;
    bf16x8 xv = *(const bf16x8*)(src + lane * 8);
    float xf[8];
    #pragma unroll
    for (int j = 0; j < 8; ++j) xf[j] = (float)xv[j];

    float s[9];
    #pragma unroll
    for (int k9 = 0; k9 < 9; ++k9) {
        const float* wr = w_conv + k9 * 512 + lane * 8;
        float4 w0 = *(const float4*)wr;
        float4 w1 = *(const float4*)(wr + 4);
        s[k9] = xf[0] * w0.x + xf[1] * w0.y + xf[2] * w0.z + xf[3] * w0.w
              + xf[4] * w1.x + xf[5] * w1.y + xf[6] * w1.z + xf[7] * w1.w;
    }
    #pragma unroll
    for (int off = 1; off < 64; off <<= 1)
        #pragma unroll
        for (int k9 = 0; k9 < 9; ++k9)
            s[k9] += __shfl_xor(s[k9], off);

    if (lane < 9) {
        int p = wid % 121;
        float v = (s[lane] + b_conv[lane]) * (g_sp[p] * (1.0f / sqrtf(1.0f + BNEPS))) + b_sp[p];
        float* dst = (wid < MROWS) ? skb + (size_t)wid * 9 : skt + (size_t)(wid - MROWS) * 9;
        dst[lane] = v;
    }
}

// ---------------------------------------------------------------------------
// channel chain (dct pool -> fc1+relu -> fc2+sigmoid+BN), one block per g.
// g==128 -> task input/output. Intermediates live in LDS only.
// ---------------------------------------------------------------------------
__global__ __launch_bounds__(256)
void channel_chain(const u16* __restrict__ Xb, const u16* __restrict__ Xt,
                   const float* __restrict__ dctT,
                   const float* __restrict__ fc1, const float* __restrict__ fc2,
                   const float* __restrict__ g_ch, const float* __restrict__ b_ch,
                   float* __restrict__ ckbuf, float* __restrict__ ck_t)
{
    __shared__ float yls[512];
    __shared__ float y2ls[32];
    const int g = blockIdx.x;
    const u16* src = (g < 128) ? Xb + (size_t)g * 121 * 512 : Xt;

    // stage 1: DCT pooling  y[c] = sum_p X[p,c]*dctT[p,c]
    for (int c = threadIdx.x; c < 512; c += 256) {
        float s = 0.f;
        for (int p = 0; p < SS; ++p)
            s += bf2f(src[(size_t)p * 512 + c]) * dctT[p * 512 + c];
        yls[c] = s;
    }
    __syncthreads();

    // stage 2: fc1 512->32 + relu (8-way k-split per output)
    {
        int o = threadIdx.x >> 3, kp = threadIdx.x & 7;
        const float* w = fc1 + (size_t)o * 512;
        float s = 0.f;
        for (int k = kp * 4; k < 512; k += 32) {
            float4 wv = *(const float4*)(w + k);
            float4 av = *(const float4*)(yls + k);
            s += wv.x * av.x + wv.y * av.y + wv.z * av.z + wv.w * av.w;
        }
        s += __shfl_xor(s, 1);
        s += __shfl_xor(s, 2);
        s += __shfl_xor(s, 4);
        if (kp == 0) y2ls[o] = fmaxf(s, 0.f);
    }
    __syncthreads();

    // stage 3: fc2 32->4608 + sigmoid + channel BN
    const float inv = 1.0f / sqrtf(1.0f + BNEPS);
    for (int o = threadIdx.x; o < CDIM * KK; o += 256) {
        const float* w = fc2 + (size_t)o * 32;
        float s = 0.f;
        #pragma unroll
        for (int k = 0; k < 32; ++k) s += y2ls[k] * w[k];
        s = 1.f / (1.f + expf(-s));
        int c = o / KK;
        s = s * (g_ch[c] * inv) + b_ch[c];
        if (g < 128) ckbuf[(size_t)g * CDIM * KK + o] = s;
        else         ck_t[o] = s;
    }
}

// tk[c*1089 + p*9 + k9] = sk_t[p*9+k9] * ck_t[c*9+k9]
__global__ void task_kernel_write(const float* __restrict__ sk_t, const float* __restrict__ ck_t,
                                  float* __restrict__ tk)
{
    int idx = blockIdx.x * blockDim.x + threadIdx.x;
    if (idx >= CDIM * SS * KK) return;
    int k9 = idx % KK;
    int pc = idx / KK;
    int p = pc % SS, c = pc / SS;
    tk[idx] = sk_t[p * KK + k9] * ck_t[c * KK + k9];
}

// ---------------------------------------------------------------------------
// final: out0[b,c,p] = (1/9) sum_k unfold(x)[k] * PS[p,k] * CS[c,k] + x[b,c,p]
// ---------------------------------------------------------------------------
__global__ __launch_bounds__(256)
void final_v2(const float* __restrict__ x, const float* __restrict__ skb,
              const float* __restrict__ sk_t, const float* __restrict__ ckbuf,
              const float* __restrict__ ck_t, float* __restrict__ out0)
{
    __shared__ float PS[SS * KK];       // 1089 fp32
    __shared__ float CS[64 * KK];       // 576 fp32
    __shared__ float XT[64 * SS];       // 7744 fp32 (64 x-planes)
    const int tid = threadIdx.x;
    const int b = blockIdx.x, c0 = blockIdx.y * 64;

    const float* sp = skb + (size_t)b * SS * KK;
    for (int i = tid; i < SS * KK; i += 256) PS[i] = sp[i] * sk_t[i];
    const float* cp = ckbuf + ((size_t)b * CDIM + c0) * KK;
    const float* tp = ck_t + (size_t)c0 * KK;
    for (int i = tid; i < 64 * KK; i += 256) CS[i] = cp[i] * tp[i];
    const float* xp = x + ((size_t)b * CDIM + c0) * SS;
    for (int i = tid; i < 64 * SS; i += 256) XT[i] = xp[i];
    __syncthreads();

    float* op = out0 + ((size_t)b * CDIM + c0) * SS;
    for (int i = tid; i < 64 * SS; i += 256) {
        int c = i / SS, p = i - c * SS;
        int h = p / 11, w = p - h * 11;
        const float* xc = XT + c * SS;
        const float* ps = PS + p * KK;
        const float* cs = CS + c * KK;
        float acc = 0.f;
        #pragma unroll
        for (int di = 0; di < 3; ++di) {
            int hh = h + di - 1;
            bool hv = (unsigned)hh < 11u;
            #pragma unroll
            for (int dj = 0; dj < 3; ++dj) {
                int ww = w + dj - 1;
                int k = di * 3 + dj;
                float xv = (hv && (unsigned)ww < 11u) ? xc[hh * 11 + ww] : 0.f;
                acc += xv * ps[k] * cs[k];
            }
        }
        op[i] = acc * (1.0f / 9.0f) + xc[p];
    }
}

extern "C" void kernel_launch(void* const* d_in, const int* in_sizes, int n_in,
                              void* d_out, int out_size, void* d_ws, size_t ws_size,
                              hipStream_t stream)
{
    const float* x      = (const float*)d_in[0];
    const float* dct_w  = (const float*)d_in[1];
    const float* w_conv = (const float*)d_in[2];
    const float* b_conv = (const float*)d_in[3];
    const float* g_sp   = (const float*)d_in[4];
    const float* b_sp   = (const float*)d_in[5];
    const float* g_ch   = (const float*)d_in[6];
    const float* b_ch   = (const float*)d_in[7];
    const float* fc1    = (const float*)d_in[8];
    const float* fc2    = (const float*)d_in[9];
    const float* up_w1  = (const float*)d_in[10];
    const float* up_b1  = (const float*)d_in[11];
    const float* up_g1  = (const float*)d_in[12];
    const float* up_bb1 = (const float*)d_in[13];
    const float* up_w2  = (const float*)d_in[14];
    const float* up_b2  = (const float*)d_in[15];
    const float* up_g2  = (const float*)d_in[16];
    const float* up_bb2 = (const float*)d_in[17];
    const float* lo_w1  = (const float*)d_in[18];
    const float* lo_b1  = (const float*)d_in[19];
    const float* lo_g1  = (const float*)d_in[20];
    const float* lo_bb1 = (const float*)d_in[21];
    const float* lo_w2  = (const float*)d_in[22];
    const float* lo_b2  = (const float*)d_in[23];
    const float* lo_g2  = (const float*)d_in[24];
    const float* lo_bb2 = (const float*)d_in[25];

    float* out0 = (float*)d_out;                       // (B,C,11,11)
    float* tk   = out0 + (size_t)BDIM_B * CDIM * SS;   // (1,C,11,11,3,3)

    // workspace layout (bytes, 64B-aligned chunks)
    char* ws = (char*)d_ws;
    size_t off = 0;
    auto alloc = [&](size_t bytes) { void* p = ws + off; off += (bytes + 63) & ~(size_t)63; return p; };
    u16*   Xb      = (u16*)alloc((size_t)MROWS * 512 * 2);
    u16*   Y1      = (u16*)alloc((size_t)MROWS * 1024 * 2);
    u16*   w1b     = (u16*)alloc((size_t)W1N * 2);
    u16*   w2b     = (u16*)alloc((size_t)W2N * 2);
    u16*   lw1b    = (u16*)alloc((size_t)L1N * 2);
    u16*   lw2b    = (u16*)alloc((size_t)L2N * 2);
    u16*   asum_b  = (u16*)alloc((size_t)128 * 1024 * 2);   // rows 121..127 unwritten
    u16*   a3b     = (u16*)alloc((size_t)128 * 1024 * 2);
    u16*   ts_pc   = (u16*)alloc((size_t)128 * 512 * 2);    // task_s (p,c) bf16
    float* dctT    = (float*)alloc((size_t)SS * 512 * 4);
    float* ckbuf   = (float*)alloc((size_t)BDIM_B * CDIM * KK * 4);
    float* skbuf   = (float*)alloc((size_t)BDIM_B * SS * KK * 4);
    float* ck_t    = (float*)alloc((size_t)CDIM * KK * 4);
    float* sk_t    = (float*)alloc((size_t)SS * KK * 4);

    // --- prep: bf16 conversions + dct transpose (one dispatch) + x transpose ---
    hipLaunchKernelGGL(transpose_x, dim3(BDIM_B, 8), dim3(256), 0, stream, x, Xb);
    hipLaunchKernelGGL(prep_all, dim3((W1N + W2N + L1N + L2N + DCTN + 255) / 256), dim3(256), 0, stream,
                       up_w1, up_w2, lo_w1, lo_w2, dct_w, w1b, w2b, lw1b, lw2b, dctT);

    // --- up path: two MFMA GEMMs (M-chunk XCD swizzle) ---
    hipLaunchKernelGGL((gemm_mfma<1, 1>), dim3(121 * 8), dim3(256), 0, stream,
                       Xb, w1b, up_b1, up_g1, up_bb1, (void*)Y1, 512, 1024, 8);
    hipLaunchKernelGGL((gemm_mfma<2, 1>), dim3(121 * 8), dim3(256), 0, stream,
                       Y1, w2b, up_b2, up_g2, up_bb2, (void*)asum_b, 1024, 1024, 8);

    // --- lo path: MFMA GEMMs on padded M=128 (rows 121..127 garbage, unread) ---
    hipLaunchKernelGGL((gemm_mfma<3, 0>), dim3(8), dim3(256), 0, stream,
                       asum_b, lw1b, lo_b1, lo_g1, lo_bb1, (void*)a3b, 1024, 1024, 8);
    hipLaunchKernelGGL((gemm_mfma<4, 0>), dim3(4), dim3(256), 0, stream,
                       a3b, lw2b, lo_b2, lo_g2, lo_bb2, (void*)ts_pc, 1024, 512, 4);

    // --- spatial kernels (instance + task fused): wave per row ---
    hipLaunchKernelGGL(rowdot9, dim3((MROWS + SS + 3) / 4), dim3(256), 0, stream,
                       Xb, ts_pc, w_conv, b_conv, g_sp, b_sp, skbuf, sk_t);

    // --- channel chain (instance + task fused, single dispatch) ---
    hipLaunchKernelGGL(channel_chain, dim3(129), dim3(256), 0, stream,
                       Xb, ts_pc, dctT, fc1, fc2, g_ch, b_ch, ckbuf, ck_t);

    // --- task kernel output ---
    hipLaunchKernelGGL(task_kernel_write, dim3((CDIM * SS * KK + 255) / 256), dim3(256), 0, stream,
                       sk_t, ck_t, tk);

    // --- final fused: factorized kernel product, LDS-staged ---
    hipLaunchKernelGGL(final_v2, dim3(BDIM_B, 8), dim3(256), 0, stream,
                       x, skbuf, sk_t, ckbuf, ck_t, out0);
}

// Round 7
// 337.617 us; speedup vs baseline: 1.0493x; 1.0417x over previous
//
#include <hip/hip_runtime.h>
#include <hip/hip_bf16.h>
#include <math.h>

#define BNEPS 1e-5f
#define BDIM_B 128
#define CDIM 512
#define SS 121
#define KK 9
#define MROWS (BDIM_B * SS)   // 15488

typedef unsigned short u16;
typedef __bf16 bf16x8 __attribute__((ext_vector_type(8)));
typedef float f32x4 __attribute__((ext_vector_type(4)));

__device__ __forceinline__ u16 f2bf(float f) {
    union { float f; unsigned int u; } v; v.f = f;
    unsigned int r = v.u + 0x7FFF + ((v.u >> 16) & 1);   // RNE
    return (u16)(r >> 16);
}
__device__ __forceinline__ float bf2f(u16 v) {
    union { unsigned int u; float f; } x; x.u = ((unsigned int)v) << 16; return x.f;
}

__device__ __forceinline__ void gld16(const u16* g, u16* l) {
    __builtin_amdgcn_global_load_lds(
        (const __attribute__((address_space(1))) void*)g,
        (__attribute__((address_space(3))) void*)l, 16, 0, 0);
}

// ---------------------------------------------------------------------------
// bf16 MFMA GEMM, 128x128 tile, BK=64 (2x 32-k subtiles per barrier pair:
// 32 MFMA between barriers -> half the barrier drains vs BK=32).
// 256 threads (4 waves, 2x2 wave grid).
// SWIZ=1 (grid 968): XCD g (=blockIdx%8) owns M-chunk bx in [g*15,g*15+15),
//   iterates all 8 N-tiles -> A-panels + B stay L2-resident (round-6 result:
//   FETCH 126->27 MB). Tail blocks 960..967 cover bx=120.
// SWIZ=0: bx = i/NT, by = i%NT (lo-path small grids).
// LDS XOR-swizzle keeps bank conflicts ~0 (round-5 result).
// A: (M,Kd) bf16 row-major.  Bw: (N,Kd) bf16 row-major (B^T form).
// epilogue: v = (acc + bias[n]) * g[n]/sqrt(1+eps) + bb[n]
// MODE 1: relu -> bf16 store to Yout[(m%121)*128 + m/121][n]  (p-major remap)
// MODE 2: block rows all one p (= bx); relu, reduce over 128 rows ->
//         bf16 asum_b[p*N + n]  (fused relu->batch-sum->bf16)
// MODE 3: relu -> bf16 store Yout[m*N+n]
// MODE 4: sigmoid -> bf16 store Yout[m*N+n]
// ---------------------------------------------------------------------------
template<int MODE, int SWIZ>
__global__ __launch_bounds__(256)
void gemm_mfma(const u16* __restrict__ A, const u16* __restrict__ Bw,
               const float* __restrict__ bias, const float* __restrict__ g,
               const float* __restrict__ bb, void* __restrict__ out,
               int Kd, int N, int NT)
{
    __shared__ __align__(16) u16 Als[2][128 * 32];
    __shared__ __align__(16) u16 Bls[2][128 * 32];

    const int tid  = threadIdx.x;
    const int lane = tid & 63;
    const int w    = tid >> 6;
    const int wm   = w >> 1, wn = w & 1;

    int bx, by;
    if (SWIZ) {
        int i = blockIdx.x;
        if (i < 960) {
            int xg = i & 7;            // XCD (round-robin block dispatch)
            int j  = i >> 3;           // 0..119
            bx = xg * 15 + (j >> 3);   // M-chunk owned by this XCD
            by = j & 7;
        } else { bx = 120; by = i - 960; }
    } else {
        bx = blockIdx.x / NT; by = blockIdx.x - bx * NT;
    }
    const int bm = bx * 128;
    const int bn = by * 128;

    f32x4 acc[4][4] = {};

    const int subrow = tid >> 2;         // 0..63
    const int kq     = tid & 3;          // 16B chunk within 32-elem k-row
    const int gchunk = kq ^ ((subrow >> 1) & 3);   // XOR-swizzled source chunk
    const u16* Ab = A  + (size_t)(bm + subrow) * Kd + gchunk * 8;
    const u16* Bb = Bw + (size_t)(bn + subrow) * Kd + gchunk * 8;
    u16* Al0  = &Als[0][(w * 16) * 32];
    u16* Al1  = &Als[0][(w * 16 + 64) * 32];
    u16* Bl0  = &Bls[0][(w * 16) * 32];
    u16* Bl1  = &Bls[0][(w * 16 + 64) * 32];
    u16* Al0b = &Als[1][(w * 16) * 32];
    u16* Al1b = &Als[1][(w * 16 + 64) * 32];
    u16* Bl0b = &Bls[1][(w * 16) * 32];
    u16* Bl1b = &Bls[1][(w * 16 + 64) * 32];

    const int fa_row = wm * 64 + (lane & 15);
    const int fb_row = wn * 64 + (lane & 15);
    const int kofs   = (((lane >> 4) ^ (((lane & 15) >> 1) & 3))) * 8;  // swizzled read chunk

    for (int k0 = 0; k0 < Kd; k0 += 64) {
        __syncthreads();
        gld16(Ab + k0,                      Al0);
        gld16(Ab + (size_t)64 * Kd + k0,    Al1);
        gld16(Bb + k0,                      Bl0);
        gld16(Bb + (size_t)64 * Kd + k0,    Bl1);
        gld16(Ab + k0 + 32,                 Al0b);
        gld16(Ab + (size_t)64 * Kd + k0 + 32, Al1b);
        gld16(Bb + k0 + 32,                 Bl0b);
        gld16(Bb + (size_t)64 * Kd + k0 + 32, Bl1b);
        __syncthreads();

        #pragma unroll
        for (int hb = 0; hb < 2; ++hb) {
            const u16* Ah = &Als[hb][0];
            const u16* Bh = &Bls[hb][0];
            bf16x8 af[4], bfv[4];
            #pragma unroll
            for (int i = 0; i < 4; ++i)
                af[i] = *(const bf16x8*)&Ah[(fa_row + i * 16) * 32 + kofs];
            #pragma unroll
            for (int j = 0; j < 4; ++j)
                bfv[j] = *(const bf16x8*)&Bh[(fb_row + j * 16) * 32 + kofs];
            #pragma unroll
            for (int i = 0; i < 4; ++i)
                #pragma unroll
                for (int j = 0; j < 4; ++j)
                    acc[i][j] = __builtin_amdgcn_mfma_f32_16x16x32_bf16(af[i], bfv[j], acc[i][j], 0, 0, 0);
        }
    }

    const float inv = 1.0f / sqrtf(1.0f + BNEPS);

    if (MODE == 1) {
        u16* Y = (u16*)out;
        int dstrow[4][4];
        #pragma unroll
        for (int i = 0; i < 4; ++i) {
            int mb = bm + wm * 64 + i * 16 + (lane >> 4) * 4;
            #pragma unroll
            for (int r = 0; r < 4; ++r) {
                int m = mb + r;
                int b = m / 121, p = m - b * 121;
                dstrow[i][r] = p * 128 + b;
            }
        }
        #pragma unroll
        for (int j = 0; j < 4; ++j) {
            int n = bn + wn * 64 + j * 16 + (lane & 15);
            float sc = g[n] * inv, bo = bias[n], bv = bb[n];
            #pragma unroll
            for (int i = 0; i < 4; ++i)
                #pragma unroll
                for (int r = 0; r < 4; ++r) {
                    float v = (acc[i][j][r] + bo) * sc + bv;
                    v = fmaxf(v, 0.0f);
                    Y[(size_t)dstrow[i][r] * N + n] = f2bf(v);
                }
        }
    } else if (MODE == 2) {
        float ps[4];
        #pragma unroll
        for (int j = 0; j < 4; ++j) {
            int n = bn + wn * 64 + j * 16 + (lane & 15);
            float sc = g[n] * inv, bo = bias[n], bv = bb[n];
            float s = 0.f;
            #pragma unroll
            for (int i = 0; i < 4; ++i)
                #pragma unroll
                for (int r = 0; r < 4; ++r) {
                    float v = (acc[i][j][r] + bo) * sc + bv;
                    s += fmaxf(v, 0.0f);
                }
            ps[j] = s;
        }
        __syncthreads();
        float* red = (float*)Als;
        #pragma unroll
        for (int j = 0; j < 4; ++j)
            red[(wm * 4 + (lane >> 4)) * 128 + wn * 64 + j * 16 + (lane & 15)] = ps[j];
        __syncthreads();
        if (tid < 128) {
            float s = 0.f;
            #pragma unroll
            for (int r = 0; r < 8; ++r) s += red[r * 128 + tid];
            ((u16*)out)[(size_t)bx * N + bn + tid] = f2bf(s);
        }
    } else {
        u16* Y = (u16*)out;
        #pragma unroll
        for (int j = 0; j < 4; ++j) {
            int n = bn + wn * 64 + j * 16 + (lane & 15);
            float sc = g[n] * inv, bo = bias[n], bv = bb[n];
            #pragma unroll
            for (int i = 0; i < 4; ++i) {
                int mb = bm + wm * 64 + i * 16 + (lane >> 4) * 4;
                #pragma unroll
                for (int r = 0; r < 4; ++r) {
                    float v = (acc[i][j][r] + bo) * sc + bv;
                    if (MODE == 3) v = fmaxf(v, 0.0f);
                    else           v = 1.f / (1.f + expf(-v));
                    Y[(size_t)(mb + r) * N + n] = f2bf(v);
                }
            }
        }
    }
}

// ---------------------------------------------------------------------------
// prep combo: blocks [0,1024): x transpose (B,C,11,11)fp32 -> Xb[(b*121+p)*512+c]bf16
//             blocks [1024,..): weight bf16 casts + dct transpose (elementwise)
// ---------------------------------------------------------------------------
#define W1N (1024 * 512)
#define W2N (1024 * 1024)
#define L1N (1024 * 1024)
#define L2N (512 * 1024)
#define DCTN (512 * 121)
#define PREP_ELEM (W1N + W2N + L1N + L2N + DCTN)
#define PREP_BLKS (1024 + (PREP_ELEM + 255) / 256)
__global__ void prep_combo(const float* __restrict__ x, u16* __restrict__ Xb,
                           const float* __restrict__ w1, const float* __restrict__ w2,
                           const float* __restrict__ l1, const float* __restrict__ l2,
                           const float* __restrict__ dct,
                           u16* __restrict__ o1, u16* __restrict__ o2,
                           u16* __restrict__ o3, u16* __restrict__ o4,
                           float* __restrict__ dctT)
{
    __shared__ float t[64 * 121];
    if (blockIdx.x < 1024) {
        int b = blockIdx.x >> 3, c0 = (blockIdx.x & 7) * 64;
        for (int idx = threadIdx.x; idx < 64 * 121; idx += 256) {
            int c = idx / 121, p = idx - c * 121;
            t[idx] = x[((size_t)b * 512 + c0 + c) * 121 + p];
        }
        __syncthreads();
        for (int idx = threadIdx.x; idx < 121 * 64; idx += 256) {
            int p = idx >> 6, c = idx & 63;
            Xb[((size_t)(b * 121 + p)) * 512 + c0 + c] = f2bf(t[c * 121 + p]);
        }
        return;
    }
    int i = (blockIdx.x - 1024) * 256 + threadIdx.x;
    if (i < W1N) { o1[i] = f2bf(w1[i]); return; }
    i -= W1N;
    if (i < W2N) { o2[i] = f2bf(w2[i]); return; }
    i -= W2N;
    if (i < L1N) { o3[i] = f2bf(l1[i]); return; }
    i -= L1N;
    if (i < L2N) { o4[i] = f2bf(l2[i]); return; }
    i -= L2N;
    if (i < DCTN) {
        int p = i >> 9, c = i & 511;
        dctT[i] = dct[(size_t)c * 121 + p];
    }
}

// ---------------------------------------------------------------------------
// sk/ck combo:
// blocks [0,3903): spatial kernel, one wave per row of (rows,512) bf16 input;
//   rows 0..15487 -> Xb -> skb; rows 15488..15608 -> ts_pc -> sk_t.
// blocks [3903,4032): channel chain (dct pool -> fc1 -> fc2+sigmoid+BN),
//   g = blk-3903; g==128 -> task.
// ---------------------------------------------------------------------------
#define ROW_BLKS ((MROWS + SS + 3) / 4)   // 3903
__global__ __launch_bounds__(256)
void skck_combo(const u16* __restrict__ Xb, const u16* __restrict__ Xt,
                const float* __restrict__ w_conv, const float* __restrict__ b_conv,
                const float* __restrict__ g_sp, const float* __restrict__ b_sp,
                const float* __restrict__ dctT,
                const float* __restrict__ fc1, const float* __restrict__ fc2,
                const float* __restrict__ g_ch, const float* __restrict__ b_ch,
                float* __restrict__ skb, float* __restrict__ skt,
                float* __restrict__ ckbuf, float* __restrict__ ck_t)
{
    __shared__ float yls[512];
    __shared__ float y2ls[32];
    const float inv = 1.0f / sqrtf(1.0f + BNEPS);

    if (blockIdx.x < ROW_BLKS) {
        int wid = (blockIdx.x * 256 + threadIdx.x) >> 6;   // global wave id = row
        int lane = threadIdx.x & 63;
        if (wid >= MROWS + SS) return;                      // wave-uniform
        const u16* src = (wid < MROWS) ? Xb + (size_t)wid * 512
                                       : Xt + (size_t)(wid - MROWS) * 512;
        bf16x8 xv = *(const bf16x8*)(src + lane * 8);
        float xf[8];
        #pragma unroll
        for (int j = 0; j < 8; ++j) xf[j] = (float)xv[j];

        float s[9];
        #pragma unroll
        for (int k9 = 0; k9 < 9; ++k9) {
            const float* wr = w_conv + k9 * 512 + lane * 8;
            float4 w0 = *(const float4*)wr;
            float4 w1 = *(const float4*)(wr + 4);
            s[k9] = xf[0] * w0.x + xf[1] * w0.y + xf[2] * w0.z + xf[3] * w0.w
                  + xf[4] * w1.x + xf[5] * w1.y + xf[6] * w1.z + xf[7] * w1.w;
        }
        #pragma unroll
        for (int off = 1; off < 64; off <<= 1)
            #pragma unroll
            for (int k9 = 0; k9 < 9; ++k9)
                s[k9] += __shfl_xor(s[k9], off);

        if (lane < 9) {
            int p = wid % 121;
            float v = (s[lane] + b_conv[lane]) * (g_sp[p] * inv) + b_sp[p];
            float* dst = (wid < MROWS) ? skb + (size_t)wid * 9 : skt + (size_t)(wid - MROWS) * 9;
            dst[lane] = v;
        }
        return;
    }

    const int g = blockIdx.x - ROW_BLKS;                    // 0..128
    const u16* src = (g < 128) ? Xb + (size_t)g * 121 * 512 : Xt;

    // stage 1: DCT pooling  y[c] = sum_p X[p,c]*dctT[p,c]
    for (int c = threadIdx.x; c < 512; c += 256) {
        float s = 0.f;
        for (int p = 0; p < SS; ++p)
            s += bf2f(src[(size_t)p * 512 + c]) * dctT[p * 512 + c];
        yls[c] = s;
    }
    __syncthreads();

    // stage 2: fc1 512->32 + relu (8-way k-split per output)
    {
        int o = threadIdx.x >> 3, kp = threadIdx.x & 7;
        const float* w = fc1 + (size_t)o * 512;
        float s = 0.f;
        for (int k = kp * 4; k < 512; k += 32) {
            float4 wv = *(const float4*)(w + k);
            float4 av = *(const float4*)(yls + k);
            s += wv.x * av.x + wv.y * av.y + wv.z * av.z + wv.w * av.w;
        }
        s += __shfl_xor(s, 1);
        s += __shfl_xor(s, 2);
        s += __shfl_xor(s, 4);
        if (kp == 0) y2ls[o] = fmaxf(s, 0.f);
    }
    __syncthreads();

    // stage 3: fc2 32->4608 + sigmoid + channel BN
    for (int o = threadIdx.x; o < CDIM * KK; o += 256) {
        const float* w = fc2 + (size_t)o * 32;
        float s = 0.f;
        #pragma unroll
        for (int k = 0; k < 32; ++k) s += y2ls[k] * w[k];
        s = 1.f / (1.f + expf(-s));
        int c = o / KK;
        s = s * (g_ch[c] * inv) + b_ch[c];
        if (g < 128) ckbuf[(size_t)g * CDIM * KK + o] = s;
        else         ck_t[o] = s;
    }
}

// ---------------------------------------------------------------------------
// final combo:
// blocks [0,1024): out0[b,c,p] = (1/9) sum_k unfold(x)[k]*PS[p,k]*CS[c,k] + x
//   (PS = sk*sk_t, CS = ck*ck_t; tk folded algebraically)
// blocks [1024,..): tk[c*1089 + p*9 + k9] = sk_t[p*9+k9] * ck_t[c*9+k9]
// ---------------------------------------------------------------------------
#define TKN (CDIM * SS * KK)              // 557568
#define FIN_BLKS (1024 + (TKN + 255) / 256)
__global__ __launch_bounds__(256)
void final_combo(const float* __restrict__ x, const float* __restrict__ skb,
                 const float* __restrict__ sk_t, const float* __restrict__ ckbuf,
                 const float* __restrict__ ck_t, float* __restrict__ out0,
                 float* __restrict__ tk)
{
    __shared__ float PS[SS * KK];       // 1089 fp32
    __shared__ float CS[64 * KK];       // 576 fp32
    __shared__ float XT[64 * SS];       // 7744 fp32

    if (blockIdx.x >= 1024) {
        int idx = (blockIdx.x - 1024) * 256 + threadIdx.x;
        if (idx < TKN) {
            int k9 = idx % KK;
            int pc = idx / KK;
            int p = pc % SS, c = pc / SS;
            tk[idx] = sk_t[p * KK + k9] * ck_t[c * KK + k9];
        }
        return;
    }

    const int tid = threadIdx.x;
    const int b = blockIdx.x >> 3, c0 = (blockIdx.x & 7) * 64;

    const float* sp = skb + (size_t)b * SS * KK;
    for (int i = tid; i < SS * KK; i += 256) PS[i] = sp[i] * sk_t[i];
    const float* cp = ckbuf + ((size_t)b * CDIM + c0) * KK;
    const float* tp = ck_t + (size_t)c0 * KK;
    for (int i = tid; i < 64 * KK; i += 256) CS[i] = cp[i] * tp[i];
    const float* xp = x + ((size_t)b * CDIM + c0) * SS;
    for (int i = tid; i < 64 * SS; i += 256) XT[i] = xp[i];
    __syncthreads();

    float* op = out0 + ((size_t)b * CDIM + c0) * SS;
    for (int i = tid; i < 64 * SS; i += 256) {
        int c = i / SS, p = i - c * SS;
        int h = p / 11, w = p - h * 11;
        const float* xc = XT + c * SS;
        const float* ps = PS + p * KK;
        const float* cs = CS + c * KK;
        float acc = 0.f;
        #pragma unroll
        for (int di = 0; di < 3; ++di) {
            int hh = h + di - 1;
            bool hv = (unsigned)hh < 11u;
            #pragma unroll
            for (int dj = 0; dj < 3; ++dj) {
                int ww = w + dj - 1;
                int k = di * 3 + dj;
                float xv = (hv && (unsigned)ww < 11u) ? xc[hh * 11 + ww] : 0.f;
                acc += xv * ps[k] * cs[k];
            }
        }
        op[i] = acc * (1.0f / 9.0f) + xc[p];
    }
}

extern "C" void kernel_launch(void* const* d_in, const int* in_sizes, int n_in,
                              void* d_out, int out_size, void* d_ws, size_t ws_size,
                              hipStream_t stream)
{
    const float* x      = (const float*)d_in[0];
    const float* dct_w  = (const float*)d_in[1];
    const float* w_conv = (const float*)d_in[2];
    const float* b_conv = (const float*)d_in[3];
    const float* g_sp   = (const float*)d_in[4];
    const float* b_sp   = (const float*)d_in[5];
    const float* g_ch   = (const float*)d_in[6];
    const float* b_ch   = (const float*)d_in[7];
    const float* fc1    = (const float*)d_in[8];
    const float* fc2    = (const float*)d_in[9];
    const float* up_w1  = (const float*)d_in[10];
    const float* up_b1  = (const float*)d_in[11];
    const float* up_g1  = (const float*)d_in[12];
    const float* up_bb1 = (const float*)d_in[13];
    const float* up_w2  = (const float*)d_in[14];
    const float* up_b2  = (const float*)d_in[15];
    const float* up_g2  = (const float*)d_in[16];
    const float* up_bb2 = (const float*)d_in[17];
    const float* lo_w1  = (const float*)d_in[18];
    const float* lo_b1  = (const float*)d_in[19];
    const float* lo_g1  = (const float*)d_in[20];
    const float* lo_bb1 = (const float*)d_in[21];
    const float* lo_w2  = (const float*)d_in[22];
    const float* lo_b2  = (const float*)d_in[23];
    const float* lo_g2  = (const float*)d_in[24];
    const float* lo_bb2 = (const float*)d_in[25];

    float* out0 = (float*)d_out;                       // (B,C,11,11)
    float* tk   = out0 + (size_t)BDIM_B * CDIM * SS;   // (1,C,11,11,3,3)

    // workspace layout (bytes, 64B-aligned chunks)
    char* ws = (char*)d_ws;
    size_t off = 0;
    auto alloc = [&](size_t bytes) { void* p = ws + off; off += (bytes + 63) & ~(size_t)63; return p; };
    u16*   Xb      = (u16*)alloc((size_t)MROWS * 512 * 2);
    u16*   Y1      = (u16*)alloc((size_t)MROWS * 1024 * 2);
    u16*   w1b     = (u16*)alloc((size_t)W1N * 2);
    u16*   w2b     = (u16*)alloc((size_t)W2N * 2);
    u16*   lw1b    = (u16*)alloc((size_t)L1N * 2);
    u16*   lw2b    = (u16*)alloc((size_t)L2N * 2);
    u16*   asum_b  = (u16*)alloc((size_t)128 * 1024 * 2);   // rows 121..127 unwritten
    u16*   a3b     = (u16*)alloc((size_t)128 * 1024 * 2);
    u16*   ts_pc   = (u16*)alloc((size_t)128 * 512 * 2);    // task_s (p,c) bf16
    float* dctT    = (float*)alloc((size_t)SS * 512 * 4);
    float* ckbuf   = (float*)alloc((size_t)BDIM_B * CDIM * KK * 4);
    float* skbuf   = (float*)alloc((size_t)BDIM_B * SS * KK * 4);
    float* ck_t    = (float*)alloc((size_t)CDIM * KK * 4);
    float* sk_t    = (float*)alloc((size_t)SS * KK * 4);

    // --- prep: x transpose + weight casts + dct transpose (one dispatch) ---
    hipLaunchKernelGGL(prep_combo, dim3(PREP_BLKS), dim3(256), 0, stream,
                       x, Xb, up_w1, up_w2, lo_w1, lo_w2, dct_w,
                       w1b, w2b, lw1b, lw2b, dctT);

    // --- up path: two MFMA GEMMs (M-chunk XCD swizzle, BK=64) ---
    hipLaunchKernelGGL((gemm_mfma<1, 1>), dim3(121 * 8), dim3(256), 0, stream,
                       Xb, w1b, up_b1, up_g1, up_bb1, (void*)Y1, 512, 1024, 8);
    hipLaunchKernelGGL((gemm_mfma<2, 1>), dim3(121 * 8), dim3(256), 0, stream,
                       Y1, w2b, up_b2, up_g2, up_bb2, (void*)asum_b, 1024, 1024, 8);

    // --- lo path: MFMA GEMMs on padded M=128 (rows 121..127 garbage, unread) ---
    hipLaunchKernelGGL((gemm_mfma<3, 0>), dim3(8), dim3(256), 0, stream,
                       asum_b, lw1b, lo_b1, lo_g1, lo_bb1, (void*)a3b, 1024, 1024, 8);
    hipLaunchKernelGGL((gemm_mfma<4, 0>), dim3(4), dim3(256), 0, stream,
                       a3b, lw2b, lo_b2, lo_g2, lo_bb2, (void*)ts_pc, 1024, 512, 4);

    // --- spatial + channel kernels (instance + task), one dispatch ---
    hipLaunchKernelGGL(skck_combo, dim3(ROW_BLKS + 129), dim3(256), 0, stream,
                       Xb, ts_pc, w_conv, b_conv, g_sp, b_sp,
                       dctT, fc1, fc2, g_ch, b_ch,
                       skbuf, sk_t, ckbuf, ck_t);

    // --- final fused + task-kernel write, one dispatch ---
    hipLaunchKernelGGL(final_combo, dim3(FIN_BLKS), dim3(256), 0, stream,
                       x, skbuf, sk_t, ckbuf, ck_t, out0, tk);
}

// Round 8
// 315.108 us; speedup vs baseline: 1.1242x; 1.0714x over previous
//
#include <hip/hip_runtime.h>
#include <hip/hip_bf16.h>
#include <math.h>

#define BNEPS 1e-5f
#define BDIM_B 128
#define CDIM 512
#define SS 121
#define KK 9
#define MROWS (BDIM_B * SS)   // 15488

typedef unsigned short u16;
typedef __bf16 bf16x8 __attribute__((ext_vector_type(8)));
typedef float f32x4 __attribute__((ext_vector_type(4)));

__device__ __forceinline__ u16 f2bf(float f) {
    union { float f; unsigned int u; } v; v.f = f;
    unsigned int r = v.u + 0x7FFF + ((v.u >> 16) & 1);   // RNE
    return (u16)(r >> 16);
}
__device__ __forceinline__ float bf2f(u16 v) {
    union { unsigned int u; float f; } x; x.u = ((unsigned int)v) << 16; return x.f;
}

__device__ __forceinline__ void gld16(const u16* g, u16* l) {
    __builtin_amdgcn_global_load_lds(
        (const __attribute__((address_space(1))) void*)g,
        (__attribute__((address_space(3))) void*)l, 16, 0, 0);
}

// ---------------------------------------------------------------------------
// bf16 MFMA GEMM, 128x128 tile, BK=64 (32 MFMA between barriers).
// SWIZ=1 (grid 968): XCD g (=blockIdx%8) owns M-chunk -> L2-resident panels
//   (round-6: FETCH 126->27 MB). SWIZ=0: bx=i/NT, by=i%NT.
// LDS XOR-swizzle keeps bank conflicts ~0 (round-5 result).
// A: (M,Kd) bf16 row-major.  Bw: (N,Kd) bf16 row-major (B^T form).
// epilogue: v = (acc + bias[n]) * g[n]/sqrt(1+eps) + bb[n]
// MODE 1: relu -> bf16 store to Yout[(m%121)*128 + m/121][n]  (p-major remap)
// MODE 2: block rows all one p (= bx); relu, reduce over 128 rows -> bf16
// MODE 3: relu -> bf16 Yout[m*N+n];  MODE 4: sigmoid -> bf16 Yout[m*N+n]
// ---------------------------------------------------------------------------
template<int MODE, int SWIZ>
__global__ __launch_bounds__(256)
void gemm_mfma(const u16* __restrict__ A, const u16* __restrict__ Bw,
               const float* __restrict__ bias, const float* __restrict__ g,
               const float* __restrict__ bb, void* __restrict__ out,
               int Kd, int N, int NT)
{
    __shared__ __align__(16) u16 Als[2][128 * 32];
    __shared__ __align__(16) u16 Bls[2][128 * 32];

    const int tid  = threadIdx.x;
    const int lane = tid & 63;
    const int w    = tid >> 6;
    const int wm   = w >> 1, wn = w & 1;

    int bx, by;
    if (SWIZ) {
        int i = blockIdx.x;
        if (i < 960) {
            int xg = i & 7;
            int j  = i >> 3;
            bx = xg * 15 + (j >> 3);
            by = j & 7;
        } else { bx = 120; by = i - 960; }
    } else {
        bx = blockIdx.x / NT; by = blockIdx.x - bx * NT;
    }
    const int bm = bx * 128;
    const int bn = by * 128;

    f32x4 acc[4][4] = {};

    const int subrow = tid >> 2;
    const int kq     = tid & 3;
    const int gchunk = kq ^ ((subrow >> 1) & 3);
    const u16* Ab = A  + (size_t)(bm + subrow) * Kd + gchunk * 8;
    const u16* Bb = Bw + (size_t)(bn + subrow) * Kd + gchunk * 8;
    u16* Al0  = &Als[0][(w * 16) * 32];
    u16* Al1  = &Als[0][(w * 16 + 64) * 32];
    u16* Bl0  = &Bls[0][(w * 16) * 32];
    u16* Bl1  = &Bls[0][(w * 16 + 64) * 32];
    u16* Al0b = &Als[1][(w * 16) * 32];
    u16* Al1b = &Als[1][(w * 16 + 64) * 32];
    u16* Bl0b = &Bls[1][(w * 16) * 32];
    u16* Bl1b = &Bls[1][(w * 16 + 64) * 32];

    const int fa_row = wm * 64 + (lane & 15);
    const int fb_row = wn * 64 + (lane & 15);
    const int kofs   = (((lane >> 4) ^ (((lane & 15) >> 1) & 3))) * 8;

    for (int k0 = 0; k0 < Kd; k0 += 64) {
        __syncthreads();
        gld16(Ab + k0,                      Al0);
        gld16(Ab + (size_t)64 * Kd + k0,    Al1);
        gld16(Bb + k0,                      Bl0);
        gld16(Bb + (size_t)64 * Kd + k0,    Bl1);
        gld16(Ab + k0 + 32,                 Al0b);
        gld16(Ab + (size_t)64 * Kd + k0 + 32, Al1b);
        gld16(Bb + k0 + 32,                 Bl0b);
        gld16(Bb + (size_t)64 * Kd + k0 + 32, Bl1b);
        __syncthreads();

        #pragma unroll
        for (int hb = 0; hb < 2; ++hb) {
            const u16* Ah = &Als[hb][0];
            const u16* Bh = &Bls[hb][0];
            bf16x8 af[4], bfv[4];
            #pragma unroll
            for (int i = 0; i < 4; ++i)
                af[i] = *(const bf16x8*)&Ah[(fa_row + i * 16) * 32 + kofs];
            #pragma unroll
            for (int j = 0; j < 4; ++j)
                bfv[j] = *(const bf16x8*)&Bh[(fb_row + j * 16) * 32 + kofs];
            #pragma unroll
            for (int i = 0; i < 4; ++i)
                #pragma unroll
                for (int j = 0; j < 4; ++j)
                    acc[i][j] = __builtin_amdgcn_mfma_f32_16x16x32_bf16(af[i], bfv[j], acc[i][j], 0, 0, 0);
        }
    }

    const float inv = 1.0f / sqrtf(1.0f + BNEPS);

    if (MODE == 1) {
        u16* Y = (u16*)out;
        int dstrow[4][4];
        #pragma unroll
        for (int i = 0; i < 4; ++i) {
            int mb = bm + wm * 64 + i * 16 + (lane >> 4) * 4;
            #pragma unroll
            for (int r = 0; r < 4; ++r) {
                int m = mb + r;
                int b = m / 121, p = m - b * 121;
                dstrow[i][r] = p * 128 + b;
            }
        }
        #pragma unroll
        for (int j = 0; j < 4; ++j) {
            int n = bn + wn * 64 + j * 16 + (lane & 15);
            float sc = g[n] * inv, bo = bias[n], bv = bb[n];
            #pragma unroll
            for (int i = 0; i < 4; ++i)
                #pragma unroll
                for (int r = 0; r < 4; ++r) {
                    float v = (acc[i][j][r] + bo) * sc + bv;
                    v = fmaxf(v, 0.0f);
                    Y[(size_t)dstrow[i][r] * N + n] = f2bf(v);
                }
        }
    } else if (MODE == 2) {
        float ps[4];
        #pragma unroll
        for (int j = 0; j < 4; ++j) {
            int n = bn + wn * 64 + j * 16 + (lane & 15);
            float sc = g[n] * inv, bo = bias[n], bv = bb[n];
            float s = 0.f;
            #pragma unroll
            for (int i = 0; i < 4; ++i)
                #pragma unroll
                for (int r = 0; r < 4; ++r) {
                    float v = (acc[i][j][r] + bo) * sc + bv;
                    s += fmaxf(v, 0.0f);
                }
            ps[j] = s;
        }
        __syncthreads();
        float* red = (float*)Als;
        #pragma unroll
        for (int j = 0; j < 4; ++j)
            red[(wm * 4 + (lane >> 4)) * 128 + wn * 64 + j * 16 + (lane & 15)] = ps[j];
        __syncthreads();
        if (tid < 128) {
            float s = 0.f;
            #pragma unroll
            for (int r = 0; r < 8; ++r) s += red[r * 128 + tid];
            ((u16*)out)[(size_t)bx * N + bn + tid] = f2bf(s);
        }
    } else {
        u16* Y = (u16*)out;
        #pragma unroll
        for (int j = 0; j < 4; ++j) {
            int n = bn + wn * 64 + j * 16 + (lane & 15);
            float sc = g[n] * inv, bo = bias[n], bv = bb[n];
            #pragma unroll
            for (int i = 0; i < 4; ++i) {
                int mb = bm + wm * 64 + i * 16 + (lane >> 4) * 4;
                #pragma unroll
                for (int r = 0; r < 4; ++r) {
                    float v = (acc[i][j][r] + bo) * sc + bv;
                    if (MODE == 3) v = fmaxf(v, 0.0f);
                    else           v = 1.f / (1.f + expf(-v));
                    Y[(size_t)(mb + r) * N + n] = f2bf(v);
                }
            }
        }
    }
}

// ---------------------------------------------------------------------------
// prep combo: blocks [0,1024): x transpose -> Xb bf16
//             blocks [1024,..): weight casts + dct transpose + w_conv pad-cast
// ---------------------------------------------------------------------------
#define W1N (1024 * 512)
#define W2N (1024 * 1024)
#define L1N (1024 * 1024)
#define L2N (512 * 1024)
#define DCTN (512 * 121)
#define WCN (16 * 512)
#define PREP_ELEM (W1N + W2N + L1N + L2N + DCTN + WCN)
#define PREP_BLKS (1024 + (PREP_ELEM + 255) / 256)
__global__ void prep_combo(const float* __restrict__ x, u16* __restrict__ Xb,
                           const float* __restrict__ w1, const float* __restrict__ w2,
                           const float* __restrict__ l1, const float* __restrict__ l2,
                           const float* __restrict__ dct, const float* __restrict__ w_conv,
                           u16* __restrict__ o1, u16* __restrict__ o2,
                           u16* __restrict__ o3, u16* __restrict__ o4,
                           float* __restrict__ dctT, u16* __restrict__ wcb)
{
    __shared__ float t[64 * 121];
    if (blockIdx.x < 1024) {
        int b = blockIdx.x >> 3, c0 = (blockIdx.x & 7) * 64;
        for (int idx = threadIdx.x; idx < 64 * 121; idx += 256) {
            int c = idx / 121, p = idx - c * 121;
            t[idx] = x[((size_t)b * 512 + c0 + c) * 121 + p];
        }
        __syncthreads();
        for (int idx = threadIdx.x; idx < 121 * 64; idx += 256) {
            int p = idx >> 6, c = idx & 63;
            Xb[((size_t)(b * 121 + p)) * 512 + c0 + c] = f2bf(t[c * 121 + p]);
        }
        return;
    }
    int i = (blockIdx.x - 1024) * 256 + threadIdx.x;
    if (i < W1N) { o1[i] = f2bf(w1[i]); return; }
    i -= W1N;
    if (i < W2N) { o2[i] = f2bf(w2[i]); return; }
    i -= W2N;
    if (i < L1N) { o3[i] = f2bf(l1[i]); return; }
    i -= L1N;
    if (i < L2N) { o4[i] = f2bf(l2[i]); return; }
    i -= L2N;
    if (i < DCTN) {
        int p = i >> 9, c = i & 511;
        dctT[i] = dct[(size_t)c * 121 + p];
        return;
    }
    i -= DCTN;
    if (i < WCN) {
        int n = i >> 9, c = i & 511;
        wcb[i] = (n < 9) ? f2bf(w_conv[(size_t)n * 512 + c]) : (u16)0;
    }
}

// ---------------------------------------------------------------------------
// spatial MFMA GEMM + channel chain, one dispatch.
// blocks [0,122): spatial kernel as GEMM (M=15609 pad, N=16 pad, K=512),
//   barrier-free, LDS-free: wave w owns 32 rows (2 16-row tiles), fragments
//   loaded straight from global (lane-quads cover contiguous 64B per row;
//   wcb 16KB stays L1-resident). Block 121 = task rows from ts_pc.
//   Epilogue: BN per p, write 9 valid cols to skb / sk_t.
// blocks [122,122+129): channel chain (dct pool -> fc1 -> fc2+sigmoid+BN),
//   g = blk-122; g==128 -> task.
// ---------------------------------------------------------------------------
__global__ __launch_bounds__(256)
void spatial_ck_combo(const u16* __restrict__ Xb, const u16* __restrict__ Xt,
                      const u16* __restrict__ wcb, const float* __restrict__ b_conv,
                      const float* __restrict__ g_sp, const float* __restrict__ b_sp,
                      const float* __restrict__ dctT,
                      const float* __restrict__ fc1, const float* __restrict__ fc2,
                      const float* __restrict__ g_ch, const float* __restrict__ b_ch,
                      float* __restrict__ skb, float* __restrict__ skt,
                      float* __restrict__ ckbuf, float* __restrict__ ck_t)
{
    const float inv = 1.0f / sqrtf(1.0f + BNEPS);

    if (blockIdx.x < 122) {
        const int tid  = threadIdx.x;
        const int lane = tid & 63;
        const int w    = tid >> 6;
        const bool task = (blockIdx.x == 121);
        const u16* Arow = task ? Xt : Xb + (size_t)blockIdx.x * 128 * 512;

        const int fr = lane & 15;
        const int kq = lane >> 4;            // 0..3
        const int r0 = w * 32;               // wave's first row (local)

        f32x4 acc0 = {}, acc1 = {};
        const u16* a0p = Arow + (size_t)(r0 + fr) * 512 + kq * 8;
        const u16* a1p = Arow + (size_t)(r0 + 16 + fr) * 512 + kq * 8;
        const u16* bp  = wcb + (size_t)fr * 512 + kq * 8;
        #pragma unroll
        for (int k0 = 0; k0 < 512; k0 += 32) {
            bf16x8 a0 = *(const bf16x8*)(a0p + k0);
            bf16x8 a1 = *(const bf16x8*)(a1p + k0);
            bf16x8 b  = *(const bf16x8*)(bp + k0);
            acc0 = __builtin_amdgcn_mfma_f32_16x16x32_bf16(a0, b, acc0, 0, 0, 0);
            acc1 = __builtin_amdgcn_mfma_f32_16x16x32_bf16(a1, b, acc1, 0, 0, 0);
        }

        int n = lane & 15;
        if (n < 9) {
            float bo = b_conv[n];
            #pragma unroll
            for (int t = 0; t < 2; ++t) {
                f32x4 a = t ? acc1 : acc0;
                #pragma unroll
                for (int r = 0; r < 4; ++r) {
                    int mloc = r0 + t * 16 + (lane >> 4) * 4 + r;
                    if (!task) {
                        int m = blockIdx.x * 128 + mloc;
                        int p = m % 121;
                        float v = (a[r] + bo) * (g_sp[p] * inv) + b_sp[p];
                        skb[(size_t)m * 9 + n] = v;
                    } else if (mloc < 121) {
                        float v = (a[r] + bo) * (g_sp[mloc] * inv) + b_sp[mloc];
                        skt[(size_t)mloc * 9 + n] = v;
                    }
                }
            }
        }
        return;
    }

    __shared__ float yls[512];
    __shared__ float y2ls[32];
    const int g = blockIdx.x - 122;                    // 0..128
    const u16* src = (g < 128) ? Xb + (size_t)g * 121 * 512 : Xt;

    // stage 1: DCT pooling  y[c] = sum_p X[p,c]*dctT[p,c]
    for (int c = threadIdx.x; c < 512; c += 256) {
        float s = 0.f;
        for (int p = 0; p < SS; ++p)
            s += bf2f(src[(size_t)p * 512 + c]) * dctT[p * 512 + c];
        yls[c] = s;
    }
    __syncthreads();

    // stage 2: fc1 512->32 + relu (8-way k-split per output)
    {
        int o = threadIdx.x >> 3, kp = threadIdx.x & 7;
        const float* w = fc1 + (size_t)o * 512;
        float s = 0.f;
        for (int k = kp * 4; k < 512; k += 32) {
            float4 wv = *(const float4*)(w + k);
            float4 av = *(const float4*)(yls + k);
            s += wv.x * av.x + wv.y * av.y + wv.z * av.z + wv.w * av.w;
        }
        s += __shfl_xor(s, 1);
        s += __shfl_xor(s, 2);
        s += __shfl_xor(s, 4);
        if (kp == 0) y2ls[o] = fmaxf(s, 0.f);
    }
    __syncthreads();

    // stage 3: fc2 32->4608 + sigmoid + channel BN
    for (int o = threadIdx.x; o < CDIM * KK; o += 256) {
        const float* w = fc2 + (size_t)o * 32;
        float s = 0.f;
        #pragma unroll
        for (int k = 0; k < 32; ++k) s += y2ls[k] * w[k];
        s = 1.f / (1.f + expf(-s));
        int c = o / KK;
        s = s * (g_ch[c] * inv) + b_ch[c];
        if (g < 128) ckbuf[(size_t)g * CDIM * KK + o] = s;
        else         ck_t[o] = s;
    }
}

// ---------------------------------------------------------------------------
// final combo:
// blocks [0,1024): out0[b,c,p] = (1/9) sum_k unfold(x)[k]*PS[p,k]*CS[c,k] + x
// blocks [1024,..): tk write
// ---------------------------------------------------------------------------
#define TKN (CDIM * SS * KK)              // 557568
#define FIN_BLKS (1024 + (TKN + 255) / 256)
__global__ __launch_bounds__(256)
void final_combo(const float* __restrict__ x, const float* __restrict__ skb,
                 const float* __restrict__ sk_t, const float* __restrict__ ckbuf,
                 const float* __restrict__ ck_t, float* __restrict__ out0,
                 float* __restrict__ tk)
{
    __shared__ float PS[SS * KK];
    __shared__ float CS[64 * KK];
    __shared__ float XT[64 * SS];

    if (blockIdx.x >= 1024) {
        int idx = (blockIdx.x - 1024) * 256 + threadIdx.x;
        if (idx < TKN) {
            int k9 = idx % KK;
            int pc = idx / KK;
            int p = pc % SS, c = pc / SS;
            tk[idx] = sk_t[p * KK + k9] * ck_t[c * KK + k9];
        }
        return;
    }

    const int tid = threadIdx.x;
    const int b = blockIdx.x >> 3, c0 = (blockIdx.x & 7) * 64;

    const float* sp = skb + (size_t)b * SS * KK;
    for (int i = tid; i < SS * KK; i += 256) PS[i] = sp[i] * sk_t[i];
    const float* cp = ckbuf + ((size_t)b * CDIM + c0) * KK;
    const float* tp = ck_t + (size_t)c0 * KK;
    for (int i = tid; i < 64 * KK; i += 256) CS[i] = cp[i] * tp[i];
    const float* xp = x + ((size_t)b * CDIM + c0) * SS;
    for (int i = tid; i < 64 * SS; i += 256) XT[i] = xp[i];
    __syncthreads();

    float* op = out0 + ((size_t)b * CDIM + c0) * SS;
    for (int i = tid; i < 64 * SS; i += 256) {
        int c = i / SS, p = i - c * SS;
        int h = p / 11, w = p - h * 11;
        const float* xc = XT + c * SS;
        const float* ps = PS + p * KK;
        const float* cs = CS + c * KK;
        float acc = 0.f;
        #pragma unroll
        for (int di = 0; di < 3; ++di) {
            int hh = h + di - 1;
            bool hv = (unsigned)hh < 11u;
            #pragma unroll
            for (int dj = 0; dj < 3; ++dj) {
                int ww = w + dj - 1;
                int k = di * 3 + dj;
                float xv = (hv && (unsigned)ww < 11u) ? xc[hh * 11 + ww] : 0.f;
                acc += xv * ps[k] * cs[k];
            }
        }
        op[i] = acc * (1.0f / 9.0f) + xc[p];
    }
}

extern "C" void kernel_launch(void* const* d_in, const int* in_sizes, int n_in,
                              void* d_out, int out_size, void* d_ws, size_t ws_size,
                              hipStream_t stream)
{
    const float* x      = (const float*)d_in[0];
    const float* dct_w  = (const float*)d_in[1];
    const float* w_conv = (const float*)d_in[2];
    const float* b_conv = (const float*)d_in[3];
    const float* g_sp   = (const float*)d_in[4];
    const float* b_sp   = (const float*)d_in[5];
    const float* g_ch   = (const float*)d_in[6];
    const float* b_ch   = (const float*)d_in[7];
    const float* fc1    = (const float*)d_in[8];
    const float* fc2    = (const float*)d_in[9];
    const float* up_w1  = (const float*)d_in[10];
    const float* up_b1  = (const float*)d_in[11];
    const float* up_g1  = (const float*)d_in[12];
    const float* up_bb1 = (const float*)d_in[13];
    const float* up_w2  = (const float*)d_in[14];
    const float* up_b2  = (const float*)d_in[15];
    const float* up_g2  = (const float*)d_in[16];
    const float* up_bb2 = (const float*)d_in[17];
    const float* lo_w1  = (const float*)d_in[18];
    const float* lo_b1  = (const float*)d_in[19];
    const float* lo_g1  = (const float*)d_in[20];
    const float* lo_bb1 = (const float*)d_in[21];
    const float* lo_w2  = (const float*)d_in[22];
    const float* lo_b2  = (const float*)d_in[23];
    const float* lo_g2  = (const float*)d_in[24];
    const float* lo_bb2 = (const float*)d_in[25];

    float* out0 = (float*)d_out;                       // (B,C,11,11)
    float* tk   = out0 + (size_t)BDIM_B * CDIM * SS;   // (1,C,11,11,3,3)

    // workspace layout (bytes, 64B-aligned chunks)
    char* ws = (char*)d_ws;
    size_t off = 0;
    auto alloc = [&](size_t bytes) { void* p = ws + off; off += (bytes + 63) & ~(size_t)63; return p; };
    u16*   Xb      = (u16*)alloc((size_t)MROWS * 512 * 2);
    u16*   Y1      = (u16*)alloc((size_t)MROWS * 1024 * 2);
    u16*   w1b     = (u16*)alloc((size_t)W1N * 2);
    u16*   w2b     = (u16*)alloc((size_t)W2N * 2);
    u16*   lw1b    = (u16*)alloc((size_t)L1N * 2);
    u16*   lw2b    = (u16*)alloc((size_t)L2N * 2);
    u16*   asum_b  = (u16*)alloc((size_t)128 * 1024 * 2);   // rows 121..127 unwritten
    u16*   a3b     = (u16*)alloc((size_t)128 * 1024 * 2);
    u16*   ts_pc   = (u16*)alloc((size_t)128 * 512 * 2);    // task_s (p,c) bf16
    float* dctT    = (float*)alloc((size_t)SS * 512 * 4);
    u16*   wcb     = (u16*)alloc((size_t)WCN * 2);          // w_conv bf16 16x512 (pad)
    float* ckbuf   = (float*)alloc((size_t)BDIM_B * CDIM * KK * 4);
    float* skbuf   = (float*)alloc((size_t)BDIM_B * SS * KK * 4);
    float* ck_t    = (float*)alloc((size_t)CDIM * KK * 4);
    float* sk_t    = (float*)alloc((size_t)SS * KK * 4);

    // --- prep: x transpose + weight casts + dct transpose + w_conv pad ---
    hipLaunchKernelGGL(prep_combo, dim3(PREP_BLKS), dim3(256), 0, stream,
                       x, Xb, up_w1, up_w2, lo_w1, lo_w2, dct_w, w_conv,
                       w1b, w2b, lw1b, lw2b, dctT, wcb);

    // --- up path: two MFMA GEMMs (M-chunk XCD swizzle, BK=64) ---
    hipLaunchKernelGGL((gemm_mfma<1, 1>), dim3(121 * 8), dim3(256), 0, stream,
                       Xb, w1b, up_b1, up_g1, up_bb1, (void*)Y1, 512, 1024, 8);
    hipLaunchKernelGGL((gemm_mfma<2, 1>), dim3(121 * 8), dim3(256), 0, stream,
                       Y1, w2b, up_b2, up_g2, up_bb2, (void*)asum_b, 1024, 1024, 8);

    // --- lo path: MFMA GEMMs on padded M=128 (rows 121..127 garbage, unread) ---
    hipLaunchKernelGGL((gemm_mfma<3, 0>), dim3(8), dim3(256), 0, stream,
                       asum_b, lw1b, lo_b1, lo_g1, lo_bb1, (void*)a3b, 1024, 1024, 8);
    hipLaunchKernelGGL((gemm_mfma<4, 0>), dim3(4), dim3(256), 0, stream,
                       a3b, lw2b, lo_b2, lo_g2, lo_bb2, (void*)ts_pc, 1024, 512, 4);

    // --- spatial MFMA GEMM + channel chain, one dispatch ---
    hipLaunchKernelGGL(spatial_ck_combo, dim3(122 + 129), dim3(256), 0, stream,
                       Xb, ts_pc, wcb, b_conv, g_sp, b_sp,
                       dctT, fc1, fc2, g_ch, b_ch,
                       skbuf, sk_t, ckbuf, ck_t);

    // --- final fused + task-kernel write, one dispatch ---
    hipLaunchKernelGGL(final_combo, dim3(FIN_BLKS), dim3(256), 0, stream,
                       x, skbuf, sk_t, ckbuf, ck_t, out0, tk);
}